// Round 4
// baseline (140.164 us; speedup 1.0000x reference)
//
#include <hip/hip_runtime.h>

// ProductSplineKAN: out[b,o] = bias[o] + sum_p ( c0 + c1*a + c2*b )
//   a = clip((x[b,2p]+1)/2, 0, 1-1e-6), b likewise odd col,
//   cell = (int(a*16), int(b*16)), c* = coeffs[p, o, ia, ib, 0..2]
//
// All kernels are PURE (write-once, value = f(inputs)) so overlapped graph
// replays are safe: no init+atomic accumulation, no read-modify-write of
// d_out or d_ws across kernel boundaries.
//  1) transpose coeffs (P,O,16,16,3) -> ct (P, cell, c, O)  [coalesced gathers]
//  2) main: block = 4 b-rows x 16 o x 4 p-slices (interleaved); 16 o-lanes
//     share a (b,p) cell -> 3x 64B coalesced lines; LDS reduce; write once.

#define D_N      768
#define O_N      16
#define P_N      384
#define GRID_N   16
#define CELLS    256
#define CSTRIDE  48                // floats per cell in transposed layout (3*16)
#define BROWS    4                 // b-rows per block
#define NPS      4                 // p-slices (waves) per block
#define XSTRIDE  772               // 768 + 4: float4-aligned, banks spread across bl

static __device__ __forceinline__ float clipnorm(float v) {
    const float CLIPMAX = (float)(1.0 - 1e-6);   // same fp32 constant as jnp.clip
    return fminf(fmaxf((v + 1.0f) * 0.5f, 0.0f), CLIPMAX);
}

// (P,O,256,3) -> (P,256,3,O); dst index t is fully coalesced on write.
__global__ void transpose_coeffs_kernel(const float* __restrict__ src,
                                        float* __restrict__ dst, int total) {
    int t = blockIdx.x * 256 + threadIdx.x;
    if (t >= total) return;
    int p    = t / (CELLS * CSTRIDE);
    int r    = t - p * (CELLS * CSTRIDE);
    int cell = r / CSTRIDE;
    int cc   = r - cell * CSTRIDE;
    int c    = cc >> 4;      // 0..2
    int o    = cc & 15;      // 0..15
    dst[t] = src[((size_t)(p * O_N + o) * CELLS + cell) * 3 + c];
}

__global__ __launch_bounds__(256) void spline_main_kernel(
        const float* __restrict__ x, const float* __restrict__ ct,
        const float* __restrict__ bias, float* __restrict__ out) {
    __shared__ float xs[BROWS * XSTRIDE];
    __shared__ float red[NPS * 64];

    int b0 = blockIdx.x * BROWS;

    // stage x[b0..b0+3][0..768) into LDS: 4*192 = 768 float4s over 256 threads
    const float* xbase = x + (size_t)b0 * D_N;
    for (int i = threadIdx.x; i < BROWS * (D_N / 4); i += 256) {
        int r  = i / (D_N / 4);
        int c4 = i - r * (D_N / 4);
        float4 v = *(const float4*)(xbase + (size_t)r * D_N + c4 * 4);
        *(float4*)(&xs[r * XSTRIDE + c4 * 4]) = v;
    }
    __syncthreads();

    int o  = threadIdx.x & 15;            // output channel
    int bl = (threadIdx.x >> 4) & (BROWS - 1);
    int ps = threadIdx.x >> 6;            // wave id = p-slice 0..3
    const float* xr = &xs[bl * XSTRIDE];
    const float* cb = ct + o;

    float acc = 0.0f;
#pragma unroll 4
    for (int p = ps; p < P_N; p += NPS) {   // interleaved: all waves share ct window
        float an = clipnorm(xr[2 * p]);
        float bn = clipnorm(xr[2 * p + 1]);
        int ia = (int)(an * 16.0f);         // an < 1 => ia <= 15
        int ib = (int)(bn * 16.0f);
        const float* cp = cb + (size_t)p * (CELLS * CSTRIDE)
                             + (ia * GRID_N + ib) * CSTRIDE;
        acc = fmaf(cp[16], an, acc + cp[0]);   // o-lanes: 64B aligned lines
        acc = fmaf(cp[32], bn, acc);
    }

    red[threadIdx.x] = acc;                  // [ps][bl*16+o]
    __syncthreads();
    if (ps == 0) {
        int t = threadIdx.x;                 // 0..63 = bl*16+o
        float s = red[t] + red[64 + t] + red[128 + t] + red[192 + t] + bias[o];
        out[(size_t)(b0 + bl) * O_N + o] = s;   // single coalesced 256B store
    }
}

// Fallback (no workspace): pure gather from original layout. Correct, slower.
__global__ void spline_naive_kernel(const float* __restrict__ x,
                                    const float* __restrict__ coeffs,
                                    const float* __restrict__ bias,
                                    float* __restrict__ out, int Btot) {
    int t = blockIdx.x * 256 + threadIdx.x;
    if (t >= Btot * O_N) return;
    int o = t & 15;
    int b = t >> 4;
    const float* xrow = x + (size_t)b * D_N;
    float acc = bias[o];
    for (int p = 0; p < P_N; ++p) {
        float an = clipnorm(xrow[2 * p]);
        float bn = clipnorm(xrow[2 * p + 1]);
        int ia = (int)(an * 16.0f);
        int ib = (int)(bn * 16.0f);
        const float* cp = coeffs + ((size_t)(p * O_N + o) * CELLS
                                    + ia * GRID_N + ib) * 3;
        acc += cp[0];
        acc = fmaf(cp[1], an, acc);
        acc = fmaf(cp[2], bn, acc);
    }
    out[t] = acc;
}

extern "C" void kernel_launch(void* const* d_in, const int* in_sizes, int n_in,
                              void* d_out, int out_size, void* d_ws, size_t ws_size,
                              hipStream_t stream) {
    const float* x      = (const float*)d_in[0];
    const float* coeffs = (const float*)d_in[1];
    const float* bias   = (const float*)d_in[2];
    float* out = (float*)d_out;

    int B = in_sizes[0] / D_N;                 // 8192
    size_t need = (size_t)P_N * CELLS * CSTRIDE * sizeof(float);  // 18.9 MB

    if (ws_size >= need && (B % BROWS) == 0) {
        float* ct = (float*)d_ws;
        int total = P_N * CELLS * CSTRIDE;
        transpose_coeffs_kernel<<<(total + 255) / 256, 256, 0, stream>>>(coeffs, ct, total);
        spline_main_kernel<<<B / BROWS, 256, 0, stream>>>(x, ct, bias, out);
    } else {
        spline_naive_kernel<<<(B * O_N + 255) / 256, 256, 0, stream>>>(x, coeffs, bias, out, B);
    }
}

// Round 8
// 112.043 us; speedup vs baseline: 1.2510x; 1.2510x over previous
//
#include <hip/hip_runtime.h>
#include <hip/hip_fp16.h>

// ProductSplineKAN: out[b,o] = bias[o] + sum_p ( c0 + c1*a + c2*b )
//   a = clip((x[b,2p]+1)/2, 0, 1-1e-6), b likewise odd col,
//   cell = (int(a*16), int(b*16)), c* = coeffs[p, o, ia, ib, 0..2]
//
// Round-5 structure (all kernels pure / write-once -> overlapped-replay safe):
//  1) build_ct16: coeffs (P,O,16,16,3) f32 -> ct (P, cell, o, {c0,c1,c2,pad}) f16
//     table 12.6 MB; one 8B ushort4 per (o,cell); 128B cell fully consumed.
//  2) stage1: p split into 8 chunks of 48, chunk = blockIdx&7 pins chunk->XCD
//     (round-robin dispatch) so each XCD L2 re-reads only its 1.6 MB slice.
//     Per block: precompute (a,b,celloff) for 16 rows x 48 p into LDS once
//     (kills the 16x per-o redundant spline math), then 48-iter gather loop:
//     ds_read_b128 + global ushort4 + 3 cvt + 3 fma. Partials -> d_ws.
//  3) stage2: out = bias + sum over 8 chunk partials.

#define D_N    768
#define O_N    16
#define P_N    384
#define GRID_N 16
#define CELLS  256
#define NCHUNK 8
#define P_CH   (P_N / NCHUNK)     // 48
#define BT     16                 // b rows per stage1 block
#define CELLB  128                // bytes per cell: 16 o * (4 halves = 8B)
#define ABO_STRIDE 52             // float4 LDS stride: 52*16B -> banks spread

static __device__ __forceinline__ float clipnorm(float v) {
    const float CLIPMAX = (float)(1.0 - 1e-6);   // same fp32 constant as jnp.clip
    return fminf(fmaxf((v + 1.0f) * 0.5f, 0.0f), CLIPMAX);
}

static __device__ __forceinline__ float h2f(unsigned short u) {
    __half_raw r; r.x = u;
    return __half2float(__half(r));
}

// (P,O,cell,3) f32 -> (P,cell,o,4) f16. Writes coalesced (8B/lane).
__global__ void build_ct16_kernel(const float* __restrict__ src,
                                  ushort4* __restrict__ dst) {
    int t = blockIdx.x * 256 + threadIdx.x;    // t = (p,cell,o); grid sized exactly
    int o    = t & 15;
    int cell = (t >> 4) & 255;
    int p    = t >> 12;
    const float* s = src + ((size_t)(p * O_N + o) * CELLS + cell) * 3;
    ushort4 v;
    v.x = __half_raw(__float2half_rn(s[0])).x;
    v.y = __half_raw(__float2half_rn(s[1])).x;
    v.z = __half_raw(__float2half_rn(s[2])).x;
    v.w = 0;
    dst[t] = v;
}

__global__ __launch_bounds__(256) void spline_stage1_kernel(
        const float* __restrict__ x, const ushort4* __restrict__ ct,
        float* __restrict__ part, int n_bo) {
    __shared__ float4 abo[BT * ABO_STRIDE];    // (an, bn, celloff_bits, -)

    int chunk = blockIdx.x & (NCHUNK - 1);     // pin chunk to XCD (round-robin)
    int btile = blockIdx.x >> 3;
    int b0 = btile * BT;

    // precompute (a, b, cell byte offset) for the 16x48 (row, p) pairs
    for (int i = threadIdx.x; i < BT * P_CH; i += 256) {
        int bl = i / P_CH;
        int pl = i - bl * P_CH;
        const float* xp = x + (size_t)(b0 + bl) * D_N + chunk * (2 * P_CH) + 2 * pl;
        float an = clipnorm(xp[0]);
        float bn = clipnorm(xp[1]);
        int ia = (int)(an * 16.0f);            // an < 1 => 0..15, no extra clip
        int ib = (int)(bn * 16.0f);
        int off = (ia * GRID_N + ib) * CELLB;
        abo[bl * ABO_STRIDE + pl] = make_float4(an, bn, __int_as_float(off), 0.0f);
    }
    __syncthreads();

    int o  = threadIdx.x & 15;
    int bl = threadIdx.x >> 4;                 // 0..15
    const char* cbase = (const char*)ct
        + (size_t)chunk * P_CH * CELLS * CELLB + o * 8;
    const float4* ab = &abo[bl * ABO_STRIDE];

    float acc = 0.0f;
#pragma unroll 4
    for (int pl = 0; pl < P_CH; ++pl) {
        float4 v = ab[pl];                     // broadcast to 16 o-lanes
        int off = __float_as_int(v.z);
        ushort4 c = *(const ushort4*)(cbase + (size_t)pl * (CELLS * CELLB) + off);
        acc += h2f(c.x);
        acc = fmaf(h2f(c.y), v.x, acc);
        acc = fmaf(h2f(c.z), v.y, acc);
    }
    // part[chunk][b][o] — one coalesced store per thread, write-once
    part[(size_t)chunk * n_bo + (size_t)(b0 + bl) * O_N + o] = acc;
}

__global__ void spline_stage2_kernel(const float* __restrict__ part,
                                     const float* __restrict__ bias,
                                     float* __restrict__ out, int n_bo) {
    int t = blockIdx.x * 256 + threadIdx.x;
    if (t >= n_bo) return;
    float s = bias[t & 15];
#pragma unroll
    for (int c = 0; c < NCHUNK; ++c) s += part[(size_t)c * n_bo + t];
    out[t] = s;
}

// Fallback (no workspace): pure gather from original layout. Correct, slower.
__global__ void spline_naive_kernel(const float* __restrict__ x,
                                    const float* __restrict__ coeffs,
                                    const float* __restrict__ bias,
                                    float* __restrict__ out, int Btot) {
    int t = blockIdx.x * 256 + threadIdx.x;
    if (t >= Btot * O_N) return;
    int o = t & 15;
    int b = t >> 4;
    const float* xrow = x + (size_t)b * D_N;
    float acc = bias[o];
    for (int p = 0; p < P_N; ++p) {
        float an = clipnorm(xrow[2 * p]);
        float bn = clipnorm(xrow[2 * p + 1]);
        int ia = (int)(an * 16.0f);
        int ib = (int)(bn * 16.0f);
        const float* cp = coeffs + ((size_t)(p * O_N + o) * CELLS
                                    + ia * GRID_N + ib) * 3;
        acc += cp[0];
        acc = fmaf(cp[1], an, acc);
        acc = fmaf(cp[2], bn, acc);
    }
    out[t] = acc;
}

extern "C" void kernel_launch(void* const* d_in, const int* in_sizes, int n_in,
                              void* d_out, int out_size, void* d_ws, size_t ws_size,
                              hipStream_t stream) {
    const float* x      = (const float*)d_in[0];
    const float* coeffs = (const float*)d_in[1];
    const float* bias   = (const float*)d_in[2];
    float* out = (float*)d_out;

    int B = in_sizes[0] / D_N;                              // 8192
    int n_bo = B * O_N;
    size_t ct_bytes   = (size_t)P_N * CELLS * CELLB;        // 12.58 MB
    size_t part_bytes = (size_t)NCHUNK * n_bo * sizeof(float);  // 4 MB

    if (ws_size >= ct_bytes + part_bytes && (B % BT) == 0) {
        ushort4* ct = (ushort4*)d_ws;
        float* part = (float*)((char*)d_ws + ct_bytes);
        build_ct16_kernel<<<(P_N * CELLS * O_N) / 256, 256, 0, stream>>>(coeffs, ct);
        spline_stage1_kernel<<<(B / BT) * NCHUNK, 256, 0, stream>>>(x, ct, part, n_bo);
        spline_stage2_kernel<<<(n_bo + 255) / 256, 256, 0, stream>>>(part, bias, out, n_bo);
    } else {
        spline_naive_kernel<<<(B * O_N + 255) / 256, 256, 0, stream>>>(x, coeffs, bias, out, B);
    }
}

// Round 9
// 109.428 us; speedup vs baseline: 1.2809x; 1.0239x over previous
//
#include <hip/hip_runtime.h>
#include <hip/hip_fp16.h>

// ProductSplineKAN: out[b,o] = bias[o] + sum_p ( c0 + c1*a + c2*b )
//   a = clip((x[b,2p]+1)/2, 0, 1-1e-6), b likewise odd col,
//   cell = (int(a*16), int(b*16)), c* = coeffs[p, o, ia, ib, 0..2]
//
// All kernels pure / write-once -> overlapped-replay safe.
//  1) build_ct16_v2: LDS-staged transpose, coalesced BOTH sides.
//     block = (p, o-half): reads 8x768 f32 contiguous (float4), emits
//     (cell, o) ushort4 {c0,c1,c2,0} as full 64B lines. Table 12.6 MB.
//  2) stage1: p split into 8 chunks of 48; chunk = blockIdx&7 pins chunk
//     to an XCD (round-robin dispatch) -> 1.6 MB slice stays L2-resident.
//     Per block: (a,b,celloff) for 16 rows x 48 p precomputed in LDS once;
//     gather loop: ds_read_b128 + 8B ushort4 + 3 cvt + 3 fma, 2 acc chains.
//  3) stage2: out = bias + sum of 8 chunk partials.

#define D_N    768
#define O_N    16
#define P_N    384
#define GRID_N 16
#define CELLS  256
#define NCHUNK 8
#define P_CH   (P_N / NCHUNK)     // 48
#define BT     16                 // b rows per stage1 block
#define CELLB  128                // bytes per cell: 16 o * 8B ushort4
#define ABO_STRIDE 52             // float4 LDS stride: banks spread

static __device__ __forceinline__ float clipnorm(float v) {
    const float CLIPMAX = (float)(1.0 - 1e-6);   // same fp32 constant as jnp.clip
    return fminf(fmaxf((v + 1.0f) * 0.5f, 0.0f), CLIPMAX);
}

static __device__ __forceinline__ float h2f(unsigned short u) {
    __half_raw r; r.x = u;
    return __half2float(__half(r));
}

// (P,O,cell,3) f32 -> (P,cell,o,4) f16, LDS-staged so global reads AND writes
// are coalesced. Grid = P_N*2 blocks of 256: block handles (p, oh=o/8).
__global__ __launch_bounds__(256) void build_ct16_v2_kernel(
        const float* __restrict__ src, ushort4* __restrict__ dst) {
    __shared__ float4 lds4[8 * 193];           // 8 o-rows x 192 f4 (+1 pad)

    int p  = blockIdx.x >> 1;
    int oh = blockIdx.x & 1;

    // read 8 x 768 floats = 1536 float4, contiguous from src
    const float4* s4 = (const float4*)src + ((size_t)(p * O_N + oh * 8) * 192);
    for (int g = threadIdx.x; g < 1536; g += 256) {
        int o = g / 192;
        int q = g - o * 192;
        lds4[o * 193 + q] = s4[g];
    }
    __syncthreads();

    // emit 256 cells x 8 o as ushort4; consecutive lanes -> consecutive dst
    const float* ldsf = (const float*)lds4;    // o-row stride = 772 floats
    ushort4* d = dst + (size_t)p * (CELLS * O_N) + oh * 8;
#pragma unroll
    for (int k = 0; k < 8; ++k) {
        int j    = k * 256 + threadIdx.x;      // j = cell*8 + o8
        int o8   = j & 7;
        int cell = j >> 3;
        int base = o8 * 772 + cell * 3;        // banks ~2-way max
        ushort4 v;
        v.x = __half_raw(__float2half_rn(ldsf[base + 0])).x;
        v.y = __half_raw(__float2half_rn(ldsf[base + 1])).x;
        v.z = __half_raw(__float2half_rn(ldsf[base + 2])).x;
        v.w = 0;
        d[(size_t)cell * O_N + o8] = v;        // full 64B lines per 8 lanes
    }
}

__global__ __launch_bounds__(256) void spline_stage1_kernel(
        const float* __restrict__ x, const ushort4* __restrict__ ct,
        float* __restrict__ part, int n_bo) {
    __shared__ float4 abo[BT * ABO_STRIDE];    // (an, bn, celloff_bits, -)

    int chunk = blockIdx.x & (NCHUNK - 1);     // pin chunk to XCD (round-robin)
    int btile = blockIdx.x >> 3;
    int b0 = btile * BT;

    // precompute (a, b, cell byte offset) for the 16x48 (row, p) pairs
    for (int i = threadIdx.x; i < BT * P_CH; i += 256) {
        int bl = i / P_CH;
        int pl = i - bl * P_CH;
        const float* xp = x + (size_t)(b0 + bl) * D_N + chunk * (2 * P_CH) + 2 * pl;
        float an = clipnorm(xp[0]);
        float bn = clipnorm(xp[1]);
        int ia = (int)(an * 16.0f);            // an < 1 => 0..15, no extra clip
        int ib = (int)(bn * 16.0f);
        int off = (ia * GRID_N + ib) * CELLB;
        abo[bl * ABO_STRIDE + pl] = make_float4(an, bn, __int_as_float(off), 0.0f);
    }
    __syncthreads();

    int o  = threadIdx.x & 15;
    int bl = threadIdx.x >> 4;                 // 0..15
    const char* cbase = (const char*)ct
        + (size_t)chunk * P_CH * CELLS * CELLB + o * 8;
    const float4* ab = &abo[bl * ABO_STRIDE];

    float acc0 = 0.0f, acc1 = 0.0f;            // 2 chains halve fma dep latency
#pragma unroll 4
    for (int pl = 0; pl < P_CH; pl += 2) {
        float4 va = ab[pl];
        float4 vb = ab[pl + 1];
        int offa = __float_as_int(va.z);
        int offb = __float_as_int(vb.z);
        ushort4 ca = *(const ushort4*)(cbase + (size_t)pl * (CELLS * CELLB) + offa);
        ushort4 cb2 = *(const ushort4*)(cbase + (size_t)(pl + 1) * (CELLS * CELLB) + offb);
        acc0 += h2f(ca.x);
        acc0 = fmaf(h2f(ca.y), va.x, acc0);
        acc0 = fmaf(h2f(ca.z), va.y, acc0);
        acc1 += h2f(cb2.x);
        acc1 = fmaf(h2f(cb2.y), vb.x, acc1);
        acc1 = fmaf(h2f(cb2.z), vb.y, acc1);
    }
    part[(size_t)chunk * n_bo + (size_t)(b0 + bl) * O_N + o] = acc0 + acc1;
}

__global__ void spline_stage2_kernel(const float* __restrict__ part,
                                     const float* __restrict__ bias,
                                     float* __restrict__ out, int n_bo) {
    int t = blockIdx.x * 256 + threadIdx.x;
    if (t >= n_bo) return;
    float s = bias[t & 15];
#pragma unroll
    for (int c = 0; c < NCHUNK; ++c) s += part[(size_t)c * n_bo + t];
    out[t] = s;
}

// Fallback (no workspace): pure gather from original layout. Correct, slower.
__global__ void spline_naive_kernel(const float* __restrict__ x,
                                    const float* __restrict__ coeffs,
                                    const float* __restrict__ bias,
                                    float* __restrict__ out, int Btot) {
    int t = blockIdx.x * 256 + threadIdx.x;
    if (t >= Btot * O_N) return;
    int o = t & 15;
    int b = t >> 4;
    const float* xrow = x + (size_t)b * D_N;
    float acc = bias[o];
    for (int p = 0; p < P_N; ++p) {
        float an = clipnorm(xrow[2 * p]);
        float bn = clipnorm(xrow[2 * p + 1]);
        int ia = (int)(an * 16.0f);
        int ib = (int)(bn * 16.0f);
        const float* cp = coeffs + ((size_t)(p * O_N + o) * CELLS
                                    + ia * GRID_N + ib) * 3;
        acc += cp[0];
        acc = fmaf(cp[1], an, acc);
        acc = fmaf(cp[2], bn, acc);
    }
    out[t] = acc;
}

extern "C" void kernel_launch(void* const* d_in, const int* in_sizes, int n_in,
                              void* d_out, int out_size, void* d_ws, size_t ws_size,
                              hipStream_t stream) {
    const float* x      = (const float*)d_in[0];
    const float* coeffs = (const float*)d_in[1];
    const float* bias   = (const float*)d_in[2];
    float* out = (float*)d_out;

    int B = in_sizes[0] / D_N;                              // 8192
    int n_bo = B * O_N;
    size_t ct_bytes   = (size_t)P_N * CELLS * CELLB;        // 12.58 MB
    size_t part_bytes = (size_t)NCHUNK * n_bo * sizeof(float);  // 4 MB

    if (ws_size >= ct_bytes + part_bytes && (B % BT) == 0) {
        ushort4* ct = (ushort4*)d_ws;
        float* part = (float*)((char*)d_ws + ct_bytes);
        build_ct16_v2_kernel<<<P_N * 2, 256, 0, stream>>>(coeffs, ct);
        spline_stage1_kernel<<<(B / BT) * NCHUNK, 256, 0, stream>>>(x, ct, part, n_bo);
        spline_stage2_kernel<<<(n_bo + 255) / 256, 256, 0, stream>>>(part, bias, out, n_bo);
    } else {
        spline_naive_kernel<<<(B * O_N + 255) / 256, 256, 0, stream>>>(x, coeffs, bias, out, B);
    }
}

// Round 15
// 108.923 us; speedup vs baseline: 1.2868x; 1.0046x over previous
//
#include <hip/hip_runtime.h>
#include <hip/hip_fp16.h>

// ProductSplineKAN: out[b,o] = bias[o] + sum_p ( c0 + c1*a + c2*b )
//   a = clip((x[b,2p]+1)/2, 0, 1-1e-6), b likewise odd col,
//   cell = (int(a*16), int(b*16)), c* = coeffs[p, o, ia, ib, 0..2]
//
// All kernels pure / write-once -> overlapped-replay safe.
//  1) build_ct16_v2: LDS-staged transpose, coalesced both sides. 12.6 MB table.
//  2) stage1: p in 8 chunks of 48 (chunk = blockIdx&7 -> XCD-pinned L2 slice).
//     (a,b,celloff) precomputed in LDS once per block; gather loop processes
//     4 p per step: 4 independent ds_read_b128 + 4 independent 8B gathers +
//     4 acc chains, fully unrolled -> high MLP (round-9's VGPR=24 serialized
//     the L2-latency chain; this is the fix under test).
//  3) stage2: out = bias + sum of 8 chunk partials (float4).

#define D_N    768
#define O_N    16
#define P_N    384
#define GRID_N 16
#define CELLS  256
#define NCHUNK 8
#define P_CH   (P_N / NCHUNK)     // 48
#define BT     16                 // b rows per stage1 block
#define CELLB  128                // bytes per cell: 16 o * 8B ushort4
#define PSTR   (CELLS * CELLB)    // 32768 B per p-plane
#define ABO_STRIDE 52             // float4 LDS stride: banks spread

static __device__ __forceinline__ float clipnorm(float v) {
    const float CLIPMAX = (float)(1.0 - 1e-6);   // same fp32 constant as jnp.clip
    return fminf(fmaxf((v + 1.0f) * 0.5f, 0.0f), CLIPMAX);
}

static __device__ __forceinline__ float h2f(unsigned short u) {
    __half_raw r; r.x = u;
    return __half2float(__half(r));
}

// (P,O,cell,3) f32 -> (P,cell,o,4) f16, LDS-staged so global reads AND writes
// are coalesced. Grid = P_N*2 blocks of 256: block handles (p, oh=o/8).
__global__ __launch_bounds__(256) void build_ct16_v2_kernel(
        const float* __restrict__ src, ushort4* __restrict__ dst) {
    __shared__ float4 lds4[8 * 193];           // 8 o-rows x 192 f4 (+1 pad)

    int p  = blockIdx.x >> 1;
    int oh = blockIdx.x & 1;

    const float4* s4 = (const float4*)src + ((size_t)(p * O_N + oh * 8) * 192);
    for (int g = threadIdx.x; g < 1536; g += 256) {
        int o = g / 192;
        int q = g - o * 192;
        lds4[o * 193 + q] = s4[g];
    }
    __syncthreads();

    const float* ldsf = (const float*)lds4;    // o-row stride = 772 floats
    ushort4* d = dst + (size_t)p * (CELLS * O_N) + oh * 8;
#pragma unroll
    for (int k = 0; k < 8; ++k) {
        int j    = k * 256 + threadIdx.x;      // j = cell*8 + o8
        int o8   = j & 7;
        int cell = j >> 3;
        int base = o8 * 772 + cell * 3;
        ushort4 v;
        v.x = __half_raw(__float2half_rn(ldsf[base + 0])).x;
        v.y = __half_raw(__float2half_rn(ldsf[base + 1])).x;
        v.z = __half_raw(__float2half_rn(ldsf[base + 2])).x;
        v.w = 0;
        d[(size_t)cell * O_N + o8] = v;        // full 64B lines per 8 lanes
    }
}

__global__ __launch_bounds__(256, 8) void spline_stage1_kernel(
        const float* __restrict__ x, const ushort4* __restrict__ ct,
        float* __restrict__ part, int n_bo) {
    __shared__ float4 abo[BT * ABO_STRIDE];    // (an, bn, celloff_bits, -)

    int chunk = blockIdx.x & (NCHUNK - 1);     // pin chunk to XCD (round-robin)
    int btile = blockIdx.x >> 3;
    int b0 = btile * BT;

    // precompute (a, b, cell byte offset) for the 16x48 (row, p) pairs
    for (int i = threadIdx.x; i < BT * P_CH; i += 256) {
        int bl = i / P_CH;
        int pl = i - bl * P_CH;
        float2 xv = *(const float2*)(x + (size_t)(b0 + bl) * D_N
                                     + chunk * (2 * P_CH) + 2 * pl);
        float an = clipnorm(xv.x);
        float bn = clipnorm(xv.y);
        int ia = (int)(an * 16.0f);            // an < 1 => 0..15, no extra clip
        int ib = (int)(bn * 16.0f);
        int off = (ia * GRID_N + ib) * CELLB;
        abo[bl * ABO_STRIDE + pl] = make_float4(an, bn, __int_as_float(off), 0.0f);
    }
    __syncthreads();

    int o  = threadIdx.x & 15;
    int bl = threadIdx.x >> 4;                 // 0..15
    const char* cbase = (const char*)ct + (size_t)chunk * P_CH * PSTR + o * 8;
    const float4* ab = &abo[bl * ABO_STRIDE];

    // 4 p per step, 4 independent load+acc chains -> MLP; full unroll
    float acc0 = 0.0f, acc1 = 0.0f, acc2 = 0.0f, acc3 = 0.0f;
#pragma unroll
    for (int pl = 0; pl < P_CH; pl += 4) {
        float4 va = ab[pl + 0];
        float4 vb = ab[pl + 1];
        float4 vc = ab[pl + 2];
        float4 vd = ab[pl + 3];
        const char* base = cbase + (size_t)pl * PSTR;
        ushort4 ca = *(const ushort4*)(base + 0 * PSTR + __float_as_int(va.z));
        ushort4 cb = *(const ushort4*)(base + 1 * PSTR + __float_as_int(vb.z));
        ushort4 cc = *(const ushort4*)(base + 2 * PSTR + __float_as_int(vc.z));
        ushort4 cd = *(const ushort4*)(base + 3 * PSTR + __float_as_int(vd.z));
        acc0 += h2f(ca.x);
        acc0 = fmaf(h2f(ca.y), va.x, acc0);
        acc0 = fmaf(h2f(ca.z), va.y, acc0);
        acc1 += h2f(cb.x);
        acc1 = fmaf(h2f(cb.y), vb.x, acc1);
        acc1 = fmaf(h2f(cb.z), vb.y, acc1);
        acc2 += h2f(cc.x);
        acc2 = fmaf(h2f(cc.y), vc.x, acc2);
        acc2 = fmaf(h2f(cc.z), vc.y, acc2);
        acc3 += h2f(cd.x);
        acc3 = fmaf(h2f(cd.y), vd.x, acc3);
        acc3 = fmaf(h2f(cd.z), vd.y, acc3);
    }
    part[(size_t)chunk * n_bo + (size_t)(b0 + bl) * O_N + o]
        = (acc0 + acc1) + (acc2 + acc3);
}

__global__ void spline_stage2_kernel(const float* __restrict__ part,
                                     const float* __restrict__ bias,
                                     float* __restrict__ out, int n_bo) {
    int t = blockIdx.x * 256 + threadIdx.x;    // t indexes float4
    if (t * 4 >= n_bo) return;
    float4 s = *(const float4*)(bias + ((t * 4) & 15));
#pragma unroll
    for (int c = 0; c < NCHUNK; ++c) {
        float4 v = *(const float4*)(part + (size_t)c * n_bo + t * 4);
        s.x += v.x; s.y += v.y; s.z += v.z; s.w += v.w;
    }
    *(float4*)(out + t * 4) = s;
}

// Fallback (no workspace): pure gather from original layout. Correct, slower.
__global__ void spline_naive_kernel(const float* __restrict__ x,
                                    const float* __restrict__ coeffs,
                                    const float* __restrict__ bias,
                                    float* __restrict__ out, int Btot) {
    int t = blockIdx.x * 256 + threadIdx.x;
    if (t >= Btot * O_N) return;
    int o = t & 15;
    int b = t >> 4;
    const float* xrow = x + (size_t)b * D_N;
    float acc = bias[o];
    for (int p = 0; p < P_N; ++p) {
        float an = clipnorm(xrow[2 * p]);
        float bn = clipnorm(xrow[2 * p + 1]);
        int ia = (int)(an * 16.0f);
        int ib = (int)(bn * 16.0f);
        const float* cp = coeffs + ((size_t)(p * O_N + o) * CELLS
                                    + ia * GRID_N + ib) * 3;
        acc += cp[0];
        acc = fmaf(cp[1], an, acc);
        acc = fmaf(cp[2], bn, acc);
    }
    out[t] = acc;
}

extern "C" void kernel_launch(void* const* d_in, const int* in_sizes, int n_in,
                              void* d_out, int out_size, void* d_ws, size_t ws_size,
                              hipStream_t stream) {
    const float* x      = (const float*)d_in[0];
    const float* coeffs = (const float*)d_in[1];
    const float* bias   = (const float*)d_in[2];
    float* out = (float*)d_out;

    int B = in_sizes[0] / D_N;                              // 8192
    int n_bo = B * O_N;
    size_t ct_bytes   = (size_t)P_N * CELLS * CELLB;        // 12.58 MB
    size_t part_bytes = (size_t)NCHUNK * n_bo * sizeof(float);  // 4 MB

    if (ws_size >= ct_bytes + part_bytes && (B % BT) == 0 && (n_bo % 1024) == 0) {
        ushort4* ct = (ushort4*)d_ws;
        float* part = (float*)((char*)d_ws + ct_bytes);
        build_ct16_v2_kernel<<<P_N * 2, 256, 0, stream>>>(coeffs, ct);
        spline_stage1_kernel<<<(B / BT) * NCHUNK, 256, 0, stream>>>(x, ct, part, n_bo);
        spline_stage2_kernel<<<n_bo / 1024, 256, 0, stream>>>(part, bias, out, n_bo);
    } else {
        spline_naive_kernel<<<(B * O_N + 255) / 256, 256, 0, stream>>>(x, coeffs, bias, out, B);
    }
}

// Round 17
// 108.836 us; speedup vs baseline: 1.2878x; 1.0008x over previous
//
#include <hip/hip_runtime.h>
#include <hip/hip_fp16.h>

// ProductSplineKAN: out[b,o] = bias[o] + sum_p ( c0 + c1*a + c2*b )
//   a = clip((x[b,2p]+1)/2, 0, 1-1e-6), b likewise odd col,
//   cell = (int(a*16), int(b*16)), c* = coeffs[p, o, ia, ib, 0..2]
//
// All kernels pure / write-once -> overlapped-replay safe.
//  1) build_ct16_v2: LDS-staged transpose, coalesced both sides. 12.6 MB table.
//  2) stage1 (round-16): p in 8 chunks of 48 (chunk = blockIdx&7 -> XCD-pinned
//     1.6 MB L2 slice). Per-(b,p) entry packed to 8 B {half2(a,b), celloff} in
//     LDS (row padded to 50 entries -> bl-groups on distinct banks), so ONE
//     ds_read_b128 serves TWO p (LDS instr halved vs r15). 8 p per unrolled
//     step = 8 independent gathers. launch_bounds(256,4): 128 VGPR, no spill.
//  3) stage2: out = bias + sum of 8 chunk partials (float4).

#define D_N    768
#define O_N    16
#define P_N    384
#define GRID_N 16
#define CELLS  256
#define NCHUNK 8
#define P_CH   (P_N / NCHUNK)     // 48
#define BT     16                 // b rows per stage1 block
#define CELLB  128                // bytes per cell: 16 o * 8B ushort4
#define PSTR   (CELLS * CELLB)    // 32768 B per p-plane
#define ABO_E  50                 // packed 8B entries per row (48 + 2 pad)

static __device__ __forceinline__ float clipnorm(float v) {
    const float CLIPMAX = (float)(1.0 - 1e-6);   // same fp32 constant as jnp.clip
    return fminf(fmaxf((v + 1.0f) * 0.5f, 0.0f), CLIPMAX);
}

static __device__ __forceinline__ float h2f(unsigned short u) {
    __half_raw r; r.x = u;
    return __half2float(__half(r));
}

// (P,O,cell,3) f32 -> (P,cell,o,4) f16, LDS-staged so global reads AND writes
// are coalesced. Grid = P_N*2 blocks of 256: block handles (p, oh=o/8).
__global__ __launch_bounds__(256) void build_ct16_v2_kernel(
        const float* __restrict__ src, ushort4* __restrict__ dst) {
    __shared__ float4 lds4[8 * 193];           // 8 o-rows x 192 f4 (+1 pad)

    int p  = blockIdx.x >> 1;
    int oh = blockIdx.x & 1;

    const float4* s4 = (const float4*)src + ((size_t)(p * O_N + oh * 8) * 192);
    for (int g = threadIdx.x; g < 1536; g += 256) {
        int o = g / 192;
        int q = g - o * 192;
        lds4[o * 193 + q] = s4[g];
    }
    __syncthreads();

    const float* ldsf = (const float*)lds4;    // o-row stride = 772 floats
    ushort4* d = dst + (size_t)p * (CELLS * O_N) + oh * 8;
#pragma unroll
    for (int k = 0; k < 8; ++k) {
        int j    = k * 256 + threadIdx.x;      // j = cell*8 + o8
        int o8   = j & 7;
        int cell = j >> 3;
        int base = o8 * 772 + cell * 3;
        ushort4 v;
        v.x = __half_raw(__float2half_rn(ldsf[base + 0])).x;
        v.y = __half_raw(__float2half_rn(ldsf[base + 1])).x;
        v.z = __half_raw(__float2half_rn(ldsf[base + 2])).x;
        v.w = 0;
        d[(size_t)cell * O_N + o8] = v;        // full 64B lines per 8 lanes
    }
}

__global__ __launch_bounds__(256, 4) void spline_stage1_kernel(
        const float* __restrict__ x, const ushort4* __restrict__ ct,
        float* __restrict__ part, int n_bo) {
    __shared__ uint2 abo[BT * ABO_E];          // {half2(an,bn), cell byte off}

    int chunk = blockIdx.x & (NCHUNK - 1);     // pin chunk to XCD (round-robin)
    int btile = blockIdx.x >> 3;
    int b0 = btile * BT;

    // precompute packed (a,b,off) for the 16x48 (row, p) pairs
    for (int i = threadIdx.x; i < BT * P_CH; i += 256) {
        int bl = i / P_CH;
        int pl = i - bl * P_CH;
        float2 xv = *(const float2*)(x + (size_t)(b0 + bl) * D_N
                                     + chunk * (2 * P_CH) + 2 * pl);
        float an = clipnorm(xv.x);
        float bn = clipnorm(xv.y);
        int ia = (int)(an * 16.0f);            // an < 1 => 0..15, no extra clip
        int ib = (int)(bn * 16.0f);
        unsigned int ab = (unsigned int)__half_raw(__float2half_rn(an)).x
                        | ((unsigned int)__half_raw(__float2half_rn(bn)).x << 16);
        abo[bl * ABO_E + pl] = make_uint2(ab, (unsigned int)((ia * GRID_N + ib) * CELLB));
    }
    __syncthreads();

    int o  = threadIdx.x & 15;
    int bl = threadIdx.x >> 4;                 // 0..15
    const char* cbase = (const char*)ct + (size_t)chunk * P_CH * PSTR + o * 8;
    const uint4* row = (const uint4*)(abo + bl * ABO_E);  // 2 entries / uint4

    float acc0 = 0.0f, acc1 = 0.0f, acc2 = 0.0f, acc3 = 0.0f;
#pragma unroll
    for (int s = 0; s < P_CH / 8; ++s) {       // 6 steps x 8 p
        uint4 eA = row[4 * s + 0];             // p = 8s+0, 8s+1
        uint4 eB = row[4 * s + 1];             // p = 8s+2, 8s+3
        uint4 eC = row[4 * s + 2];             // p = 8s+4, 8s+5
        uint4 eD = row[4 * s + 3];             // p = 8s+6, 8s+7
        const char* bs = cbase + (size_t)(8 * s) * PSTR;
        ushort4 c0 = *(const ushort4*)(bs + 0 * PSTR + (int)eA.y);
        ushort4 c1 = *(const ushort4*)(bs + 1 * PSTR + (int)eA.w);
        ushort4 c2 = *(const ushort4*)(bs + 2 * PSTR + (int)eB.y);
        ushort4 c3 = *(const ushort4*)(bs + 3 * PSTR + (int)eB.w);
        ushort4 c4 = *(const ushort4*)(bs + 4 * PSTR + (int)eC.y);
        ushort4 c5 = *(const ushort4*)(bs + 5 * PSTR + (int)eC.w);
        ushort4 c6 = *(const ushort4*)(bs + 6 * PSTR + (int)eD.y);
        ushort4 c7 = *(const ushort4*)(bs + 7 * PSTR + (int)eD.w);

        acc0 += h2f(c0.x);
        acc0 = fmaf(h2f(c0.y), h2f((unsigned short)(eA.x & 0xffff)), acc0);
        acc0 = fmaf(h2f(c0.z), h2f((unsigned short)(eA.x >> 16)), acc0);
        acc1 += h2f(c1.x);
        acc1 = fmaf(h2f(c1.y), h2f((unsigned short)(eA.z & 0xffff)), acc1);
        acc1 = fmaf(h2f(c1.z), h2f((unsigned short)(eA.z >> 16)), acc1);
        acc2 += h2f(c2.x);
        acc2 = fmaf(h2f(c2.y), h2f((unsigned short)(eB.x & 0xffff)), acc2);
        acc2 = fmaf(h2f(c2.z), h2f((unsigned short)(eB.x >> 16)), acc2);
        acc3 += h2f(c3.x);
        acc3 = fmaf(h2f(c3.y), h2f((unsigned short)(eB.z & 0xffff)), acc3);
        acc3 = fmaf(h2f(c3.z), h2f((unsigned short)(eB.z >> 16)), acc3);
        acc0 += h2f(c4.x);
        acc0 = fmaf(h2f(c4.y), h2f((unsigned short)(eC.x & 0xffff)), acc0);
        acc0 = fmaf(h2f(c4.z), h2f((unsigned short)(eC.x >> 16)), acc0);
        acc1 += h2f(c5.x);
        acc1 = fmaf(h2f(c5.y), h2f((unsigned short)(eC.z & 0xffff)), acc1);
        acc1 = fmaf(h2f(c5.z), h2f((unsigned short)(eC.z >> 16)), acc1);
        acc2 += h2f(c6.x);
        acc2 = fmaf(h2f(c6.y), h2f((unsigned short)(eD.x & 0xffff)), acc2);
        acc2 = fmaf(h2f(c6.z), h2f((unsigned short)(eD.x >> 16)), acc2);
        acc3 += h2f(c7.x);
        acc3 = fmaf(h2f(c7.y), h2f((unsigned short)(eD.z & 0xffff)), acc3);
        acc3 = fmaf(h2f(c7.z), h2f((unsigned short)(eD.z >> 16)), acc3);
    }
    part[(size_t)chunk * n_bo + (size_t)(b0 + bl) * O_N + o]
        = (acc0 + acc1) + (acc2 + acc3);
}

__global__ void spline_stage2_kernel(const float* __restrict__ part,
                                     const float* __restrict__ bias,
                                     float* __restrict__ out, int n_bo) {
    int t = blockIdx.x * 256 + threadIdx.x;    // t indexes float4
    if (t * 4 >= n_bo) return;
    float4 s = *(const float4*)(bias + ((t * 4) & 15));
#pragma unroll
    for (int c = 0; c < NCHUNK; ++c) {
        float4 v = *(const float4*)(part + (size_t)c * n_bo + t * 4);
        s.x += v.x; s.y += v.y; s.z += v.z; s.w += v.w;
    }
    *(float4*)(out + t * 4) = s;
}

// Fallback (no workspace): pure gather from original layout. Correct, slower.
__global__ void spline_naive_kernel(const float* __restrict__ x,
                                    const float* __restrict__ coeffs,
                                    const float* __restrict__ bias,
                                    float* __restrict__ out, int Btot) {
    int t = blockIdx.x * 256 + threadIdx.x;
    if (t >= Btot * O_N) return;
    int o = t & 15;
    int b = t >> 4;
    const float* xrow = x + (size_t)b * D_N;
    float acc = bias[o];
    for (int p = 0; p < P_N; ++p) {
        float an = clipnorm(xrow[2 * p]);
        float bn = clipnorm(xrow[2 * p + 1]);
        int ia = (int)(an * 16.0f);
        int ib = (int)(bn * 16.0f);
        const float* cp = coeffs + ((size_t)(p * O_N + o) * CELLS
                                    + ia * GRID_N + ib) * 3;
        acc += cp[0];
        acc = fmaf(cp[1], an, acc);
        acc = fmaf(cp[2], bn, acc);
    }
    out[t] = acc;
}

extern "C" void kernel_launch(void* const* d_in, const int* in_sizes, int n_in,
                              void* d_out, int out_size, void* d_ws, size_t ws_size,
                              hipStream_t stream) {
    const float* x      = (const float*)d_in[0];
    const float* coeffs = (const float*)d_in[1];
    const float* bias   = (const float*)d_in[2];
    float* out = (float*)d_out;

    int B = in_sizes[0] / D_N;                              // 8192
    int n_bo = B * O_N;
    size_t ct_bytes   = (size_t)P_N * CELLS * CELLB;        // 12.58 MB
    size_t part_bytes = (size_t)NCHUNK * n_bo * sizeof(float);  // 4 MB

    if (ws_size >= ct_bytes + part_bytes && (B % BT) == 0 && (n_bo % 1024) == 0) {
        ushort4* ct = (ushort4*)d_ws;
        float* part = (float*)((char*)d_ws + ct_bytes);
        build_ct16_v2_kernel<<<P_N * 2, 256, 0, stream>>>(coeffs, ct);
        spline_stage1_kernel<<<(B / BT) * NCHUNK, 256, 0, stream>>>(x, ct, part, n_bo);
        spline_stage2_kernel<<<n_bo / 1024, 256, 0, stream>>>(part, bias, out, n_bo);
    } else {
        spline_naive_kernel<<<(B * O_N + 255) / 256, 256, 0, stream>>>(x, coeffs, bias, out, B);
    }
}